// Round 1
// baseline (202.518 us; speedup 1.0000x reference)
//
#include <hip/hip_runtime.h>

#define BN 4
#define NH 4
#define DK 16
#define HD 64
#define CQ 256
#define WQ 4096
#define WKV 4096

typedef unsigned short u16;
typedef __attribute__((ext_vector_type(8))) short bf16x8;
typedef __attribute__((ext_vector_type(4))) float f32x4;

__device__ inline u16 f2bf(float f) {
    unsigned int u = __float_as_uint(f);
    unsigned int r = (u + 0x7FFFu + ((u >> 16) & 1u)) >> 16;
    return (u16)r;
}

// Phase 1: 1x1-conv projections.
// grid = B(4) * wchunk(16) * ogroup(2) * proj(3) = 384 blocks, 256 threads.
// Each thread: one w, 32 output channels, K=256 reduction.
__global__ __launch_bounds__(256) void proj_kernel(
    const float* __restrict__ x_q, const float* __restrict__ x_kv,
    const float* __restrict__ wq, const float* __restrict__ bq,
    const float* __restrict__ wk, const float* __restrict__ bk,
    const float* __restrict__ wv, const float* __restrict__ bv,
    u16* __restrict__ qb, u16* __restrict__ kb, float* __restrict__ vf)
{
    int blk = blockIdx.x;
    int p   = blk % 3;
    int og  = (blk / 3) & 1;
    int wch = (blk / 6) & 15;
    int b   = blk / 96;
    int w = wch * 256 + threadIdx.x;

    const float* x    = (p == 0) ? x_q : x_kv;
    const float* wgt  = (p == 0) ? wq : (p == 1 ? wk : wv);
    const float* bias = (p == 0) ? bq : (p == 1 ? bk : bv);

    float acc[32];
    #pragma unroll
    for (int i = 0; i < 32; ++i) acc[i] = 0.f;

    const float* xp = x + (size_t)b * CQ * WQ + w;
    #pragma unroll 4
    for (int c = 0; c < CQ; ++c) {
        float xv = xp[(size_t)c * WQ];
        #pragma unroll
        for (int oo = 0; oo < 32; ++oo)
            acc[oo] += wgt[(og * 32 + oo) * CQ + c] * xv;  // uniform -> s_load
    }

    #pragma unroll
    for (int oo = 0; oo < 32; ++oo) {
        int o = og * 32 + oo;
        float val = acc[oo] + bias[o];
        int h = o >> 4, d = o & 15;
        size_t idx = ((size_t)(b * NH + h) * WQ + w) * DK + d;
        if (p == 2) {
            vf[idx] = val;
        } else if (p == 0) {
            qb[idx] = f2bf(val);
        } else {
            kb[idx] = f2bf(val);
        }
    }
}

// Phase 2: g[bh,k] = sum_q sigmoid(q . k) via 16x16x32 bf16 MFMA (K padded 16->32).
// One wave per (bh, ktile16): 16*256 = 4096 waves = 1024 blocks x 256 threads.
__global__ __launch_bounds__(256) void logits_kernel(
    const u16* __restrict__ qb, const u16* __restrict__ kb,
    float* __restrict__ g)
{
    int wave = (blockIdx.x * 256 + (int)threadIdx.x) >> 6;
    int lane = threadIdx.x & 63;
    int bh = wave >> 8;      // 0..15
    int kt = wave & 255;     // k-tile index
    int row  = lane & 15;
    int half = lane >> 4;    // 0..3
    int d0   = (half & 1) * 8;
    bool hi  = (half >= 2);  // these lane groups carry k=16..31 -> zero pad

    const bf16x8 zv = {0, 0, 0, 0, 0, 0, 0, 0};

    bf16x8 bfrag = *(const bf16x8*)(kb + (((size_t)bh * WKV + kt * 16 + row) * DK + d0));
    if (hi) bfrag = zv;

    const u16* qp = qb + (((size_t)bh * WQ + row) * DK + d0);

    float g0 = 0.f, g1 = 0.f, g2 = 0.f, g3 = 0.f;
    const float NL2E = -1.44269504088896340736f;
    #pragma unroll 2
    for (int qt = 0; qt < WQ / 16; ++qt) {
        bf16x8 a = *(const bf16x8*)(qp + (size_t)qt * 16 * DK);
        if (hi) a = zv;
        f32x4 c = {0.f, 0.f, 0.f, 0.f};
        c = __builtin_amdgcn_mfma_f32_16x16x32_bf16(a, bfrag, c, 0, 0, 0);
        g0 += __builtin_amdgcn_rcpf(1.f + __builtin_amdgcn_exp2f(NL2E * c[0]));
        g1 += __builtin_amdgcn_rcpf(1.f + __builtin_amdgcn_exp2f(NL2E * c[1]));
        g2 += __builtin_amdgcn_rcpf(1.f + __builtin_amdgcn_exp2f(NL2E * c[2]));
        g3 += __builtin_amdgcn_rcpf(1.f + __builtin_amdgcn_exp2f(NL2E * c[3]));
    }
    float gacc = (g0 + g1) + (g2 + g3);
    // sum over the 4 lane-groups holding the 16 rows of this column
    gacc += __shfl_xor(gacc, 16, 64);
    gacc += __shfl_xor(gacc, 32, 64);
    if (lane < 16)
        g[(size_t)bh * WKV + kt * 16 + lane] = gacc;
}

// Phase 3+4: S[bh,d] = sum_k g*v ; pooled = S/(Wq*Wkv) ; out = wo@pooled + bo.
// grid = B blocks, 256 threads (h = t>>6, kg = (t>>4)&3, d = t&15).
__global__ __launch_bounds__(256) void reduce_out_kernel(
    const float* __restrict__ g, const float* __restrict__ vf,
    const float* __restrict__ wo, const float* __restrict__ bo,
    float* __restrict__ out)
{
    __shared__ float red[256];
    __shared__ float pooled[HD];
    int b = blockIdx.x, t = threadIdx.x;
    int d = t & 15, kg = (t >> 4) & 3, h = t >> 6;
    int bh = b * NH + h;
    const float* gp = g + (size_t)bh * WKV;
    const float* vp = vf + (size_t)bh * WKV * DK + d;
    float s = 0.f;
    for (int i = 0; i < WKV / 4; ++i) {
        int k = kg * (WKV / 4) + i;
        s += gp[k] * vp[(size_t)k * DK];
    }
    red[t] = s;
    __syncthreads();
    if (kg == 0) {
        float S = red[t] + red[t + 16] + red[t + 32] + red[t + 48];
        pooled[h * DK + d] = S * (1.f / ((float)WQ * (float)WKV));
    }
    __syncthreads();
    float val = bo[t];
    #pragma unroll
    for (int c2 = 0; c2 < HD; ++c2)
        val += wo[t * HD + c2] * pooled[c2];
    out[b * CQ + t] = val;
}

extern "C" void kernel_launch(void* const* d_in, const int* in_sizes, int n_in,
                              void* d_out, int out_size, void* d_ws, size_t ws_size,
                              hipStream_t stream) {
    const float* x_q  = (const float*)d_in[0];
    const float* x_kv = (const float*)d_in[1];
    const float* wq   = (const float*)d_in[2];
    const float* bq   = (const float*)d_in[3];
    const float* wk   = (const float*)d_in[4];
    const float* bk   = (const float*)d_in[5];
    const float* wv   = (const float*)d_in[6];
    const float* bv   = (const float*)d_in[7];
    const float* wo   = (const float*)d_in[8];
    const float* bo   = (const float*)d_in[9];
    float* out = (float*)d_out;

    char* ws = (char*)d_ws;
    u16*   qb = (u16*)ws;                      // 16*4096*16 bf16 = 2 MB
    u16*   kb = (u16*)(ws + (2u << 20));       // 2 MB
    float* vf = (float*)(ws + (4u << 20));     // 16*4096*16 f32 = 4 MB
    float* g  = (float*)(ws + (8u << 20));     // 16*4096 f32 = 256 KB

    proj_kernel<<<384, 256, 0, stream>>>(x_q, x_kv, wq, bq, wk, bk, wv, bv, qb, kb, vf);
    logits_kernel<<<1024, 256, 0, stream>>>(qb, kb, g);
    reduce_out_kernel<<<BN, 256, 0, stream>>>(g, vf, wo, bo, out);
}